// Round 5
// baseline (879.240 us; speedup 1.0000x reference)
//
#include <hip/hip_runtime.h>
#include <hip/hip_bf16.h>
#include <stdint.h>

// Problem constants
#define T_TREES 16
#define B_ROWS  8192
#define DIN     512
#define DH      1024
#define DOUT    256

typedef unsigned short u16;
typedef __attribute__((ext_vector_type(8))) short short8;
typedef __attribute__((ext_vector_type(16))) float floatx16;

// round-to-nearest-even fp32 -> bf16
__device__ __forceinline__ u16 f2bf(float f) {
    union { float f; uint32_t u; } v; v.f = f;
    uint32_t u = v.u;
    uint32_t r = (u + 0x7fffu + ((u >> 16) & 1u)) >> 16;
    return (u16)r;
}

// async 16B/lane global->LDS (lands at wave-uniform base + lane*16)
__device__ __forceinline__ void async_copy16(const u16* g, u16* l) {
    __builtin_amdgcn_global_load_lds(
        (const __attribute__((address_space(1))) uint32_t*)g,
        (__attribute__((address_space(3))) uint32_t*)l,
        16, 0, 0);
}

// ---------------------------------------------------------------------------
// Fused: convert x (fp32->bf16) + init out with mean bias.
// x: 8192*512 floats = 1,048,576 float4 -> 4096 blocks (ROUND-4 BUG: was 1024)
// out: 8192*256 = 2,097,152 elems -> 8192 blocks
__global__ void setup_kernel(const float* __restrict__ x, u16* __restrict__ xb,
                             const float* __restrict__ b3, float* __restrict__ out) {
    if (blockIdx.x < 4096) {
        int idx = blockIdx.x * 256 + threadIdx.x;  // 1,048,576 float4 groups
        float4 v = ((const float4*)x)[idx];
        ushort4 o;
        o.x = f2bf(v.x); o.y = f2bf(v.y); o.z = f2bf(v.z); o.w = f2bf(v.w);
        ((ushort4*)xb)[idx] = o;
    } else {
        int idx = (blockIdx.x - 4096) * 256 + threadIdx.x;  // 2M out elems
        int o = idx & (DOUT - 1);
        float s = 0.f;
#pragma unroll
        for (int t = 0; t < T_TREES; t++) s += b3[t * DOUT + o];
        out[idx] = s * (1.f / T_TREES);
    }
}

// Fused convert+transpose for all three weights: fp32 [T][K][N] -> bf16 [T][N][K].
// grid.x = 512 (W1) + 1024 (W2) + 256 (W3) tiles of 32x32, grid.z = T.
__global__ void convert_weights_kernel(const float* __restrict__ W1, const float* __restrict__ W2,
                                       const float* __restrict__ W3,
                                       u16* __restrict__ W1b, u16* __restrict__ W2b,
                                       u16* __restrict__ W3b) {
    __shared__ float tile[32][33];
    int t = blockIdx.z, tl = blockIdx.x;
    const float* in; u16* out; int K, N, kt, nt; float scale = 1.f;
    if (tl < 512)       { in = W1; out = W1b; K = DIN; N = DH;   kt = tl & 15; nt = tl >> 4; }
    else if (tl < 1536) { tl -= 512;  in = W2; out = W2b; K = DH; N = DH;   kt = tl & 31; nt = tl >> 5; }
    else                { tl -= 1536; in = W3; out = W3b; K = DH; N = DOUT; kt = tl & 31; nt = tl >> 5;
                          scale = 1.f / T_TREES; }
    int k0 = kt * 32, n0 = nt * 32;
    const float* inb = in + (size_t)t * K * N;
    u16* outb = out + (size_t)t * K * N;
    int c = threadIdx.x & 31, rg = threadIdx.x >> 5;
#pragma unroll
    for (int i = 0; i < 4; i++) {
        int r = rg * 4 + i;
        tile[r][c] = inb[(size_t)(k0 + r) * N + n0 + c];
    }
    __syncthreads();
#pragma unroll
    for (int i = 0; i < 4; i++) {
        int r = rg * 4 + i;
        outb[(size_t)(n0 + r) * K + k0 + c] = f2bf(tile[c][r] * scale);
    }
}

// ---------------------------------------------------------------------------
// 32x32x16-MFMA GEMM core. Block 128x128, 4 waves 2x2 of 64x64, each wave
// 2x2 frags of 32x32. BK=64 slab (32 KB LDS).
//
// LDS swizzle: row r stores global elem-col c at LDS col c ^ ((r&3)*16).
//  - frag read (b128, fixed kq): 8 dwords/bank (minimum aliasing).
//  - staging instr j covers rows j*8+s (s=lane>>3); lane chunk c8=lane&7 lands
//    at LDS elem col c8*8, so it READs global col ((c8 ^ ((s&3)<<1))<<3;
//    per-s global reads remain a full contiguous 128 B row (permuted order).
//  - DMA LDS writes are base+lane*16 contiguous: conflict-free.
//
// A/B frag: lane reads [row=lane&31][k = (lane>>5)*8 .. +7] as one b128
// (any A/B-consistent k bijection is contraction-invariant). C/D:
// col=lane&31, row=(reg&3)+8*(reg>>2)+4*(lane>>5)  [measured m74/m101].

#define GEMM_PREAMBLE()                                          \
    const int tid = threadIdx.x;                                 \
    const int wave = tid >> 6;                                   \
    const int lane = tid & 63;                                   \
    const int l31 = lane & 31;                                   \
    const int h = lane >> 5;                                     \
    const int rb = l31 & 3;        /* row&3 for frag reads */    \
    const int wm = (wave >> 1) * 64;                             \
    const int wn = (wave & 1) * 64;                              \
    const int s = lane >> 3;       /* staging row in instr */    \
    const int c8 = lane & 7;                                     \
    const int colElem = ((c8 ^ ((s & 3) << 1)) << 3);

#define GEMM_KSLAB(Ab, Bb, K)                                                         \
    {                                                                                  \
        _Pragma("unroll")                                                              \
        for (int i = 0; i < 4; i++) {                                                  \
            const int j = wave * 4 + i;                                                \
            const int r = j * 8 + s;                                                   \
            async_copy16(Ab + (size_t)(m0 + r) * K + kk + colElem, &ldsA[j * 512]);    \
            async_copy16(Bb + (size_t)(n0 + r) * K + kk + colElem, &ldsB[j * 512]);    \
        }                                                                              \
        __syncthreads();                                                               \
        _Pragma("unroll")                                                              \
        for (int kq = 0; kq < 4; kq++) {                                               \
            const int col = ((kq ^ rb) << 4) + h * 8;                                  \
            short8 a[2], b[2];                                                         \
            _Pragma("unroll")                                                          \
            for (int fi = 0; fi < 2; fi++)                                             \
                a[fi] = *(const short8*)&ldsA[(wm + fi * 32 + l31) * 64 + col];        \
            _Pragma("unroll")                                                          \
            for (int fj = 0; fj < 2; fj++)                                             \
                b[fj] = *(const short8*)&ldsB[(wn + fj * 32 + l31) * 64 + col];        \
            _Pragma("unroll")                                                          \
            for (int fi = 0; fi < 2; fi++)                                             \
                _Pragma("unroll")                                                      \
                for (int fj = 0; fj < 2; fj++)                                         \
                    acc[fi][fj] = __builtin_amdgcn_mfma_f32_32x32x16_bf16(             \
                        a[fi], b[fj], acc[fi][fj], 0, 0, 0);                           \
        }                                                                              \
        __syncthreads();                                                               \
    }

// Batched GEMM + bias + ReLU, bf16 out.  C[t] = relu(A[t] @ B[t]^T + bias[t])
__global__ __launch_bounds__(256, 2)
void gemm_relu_bf16(const u16* __restrict__ A, size_t aStrideT,
                    const u16* __restrict__ Bt,
                    const float* __restrict__ bias,
                    u16* __restrict__ C,
                    int M, int N, int K) {
    __shared__ u16 ldsA[128 * 64];
    __shared__ u16 ldsB[128 * 64];

    const int t = blockIdx.z;
    const u16* Ab = A + (size_t)t * aStrideT;
    const u16* Bb = Bt + (size_t)t * (size_t)N * K;
    u16* Cb = C + (size_t)t * (size_t)M * N;
    const float* biasb = bias + (size_t)t * N;

    const int m0 = blockIdx.x * 128;
    const int n0 = blockIdx.y * 128;

    GEMM_PREAMBLE();

    floatx16 acc[2][2];
#pragma unroll
    for (int fi = 0; fi < 2; fi++)
#pragma unroll
        for (int fj = 0; fj < 2; fj++)
#pragma unroll
            for (int r = 0; r < 16; r++) acc[fi][fj][r] = 0.f;

    for (int kk = 0; kk < K; kk += 64) GEMM_KSLAB(Ab, Bb, K);

    // epilogue: per reg, 64 lanes cover 2 rows x 32 contiguous cols = 2x64B segs
#pragma unroll
    for (int fj = 0; fj < 2; fj++) {
        const int n = n0 + wn + fj * 32 + l31;
        const float bv = biasb[n];
#pragma unroll
        for (int fi = 0; fi < 2; fi++) {
#pragma unroll
            for (int r = 0; r < 16; r++) {
                const int m = m0 + wm + fi * 32 + (r & 3) + 8 * (r >> 2) + 4 * h;
                float v = acc[fi][fj][r] + bv;
                v = v > 0.f ? v : 0.f;
                Cb[(size_t)m * N + n] = f2bf(v);
            }
        }
    }
}

// Final layer + mean over trees: z = tree, fp32 atomicAdd into pre-biased Out.
// H2 bf16 [g][M][DH]; W3t bf16 [g][DOUT][DH] (pre-scaled by 1/16).
__global__ __launch_bounds__(256, 2)
void gemm_final(const u16* __restrict__ H2, const u16* __restrict__ W3t,
                float* __restrict__ Out) {
    constexpr int M = B_ROWS, N = DOUT, K = DH;
    __shared__ u16 ldsA[128 * 64];
    __shared__ u16 ldsB[128 * 64];

    const int m0 = blockIdx.x * 128;
    const int n0 = blockIdx.y * 128;
    const int t = blockIdx.z;
    const u16* Ab = H2 + (size_t)t * M * K;
    const u16* Bb = W3t + (size_t)t * N * K;

    GEMM_PREAMBLE();

    floatx16 acc[2][2];
#pragma unroll
    for (int fi = 0; fi < 2; fi++)
#pragma unroll
        for (int fj = 0; fj < 2; fj++)
#pragma unroll
            for (int r = 0; r < 16; r++) acc[fi][fj][r] = 0.f;

    for (int kk = 0; kk < K; kk += 64) GEMM_KSLAB(Ab, Bb, K);

#pragma unroll
    for (int fj = 0; fj < 2; fj++) {
        const int n = n0 + wn + fj * 32 + l31;
#pragma unroll
        for (int fi = 0; fi < 2; fi++) {
#pragma unroll
            for (int r = 0; r < 16; r++) {
                const int m = m0 + wm + fi * 32 + (r & 3) + 8 * (r >> 2) + 4 * h;
                atomicAdd(&Out[(size_t)m * N + n], acc[fi][fj][r]);
            }
        }
    }
}

// ---------------------------------------------------------------------------
extern "C" void kernel_launch(void* const* d_in, const int* in_sizes, int n_in,
                              void* d_out, int out_size, void* d_ws, size_t ws_size,
                              hipStream_t stream) {
    const float* x  = (const float*)d_in[0];
    const float* W1 = (const float*)d_in[1];
    const float* b1 = (const float*)d_in[2];
    const float* W2 = (const float*)d_in[3];
    const float* b2 = (const float*)d_in[4];
    const float* W3 = (const float*)d_in[5];
    const float* b3 = (const float*)d_in[6];
    float* out = (float*)d_out;

    // workspace: fixed 64 MB (xb 8 + W1b 16 + W2b 32 + W3b 8), then h1/h2
    const size_t XB_BYTES = 8388608ull;
    const size_t W1B_BYTES = 16777216ull, W2B_BYTES = 33554432ull, W3B_BYTES = 8388608ull;
    const size_t FIXED = XB_BYTES + W1B_BYTES + W2B_BYTES + W3B_BYTES;  // 67,108,864
    const size_t PER_TREE = 33554432ull;  // h1 16 MB + h2 16 MB

    uint8_t* ws = (uint8_t*)d_ws;
    u16* xb  = (u16*)ws;
    u16* W1b = (u16*)(ws + XB_BYTES);
    u16* W2b = (u16*)(ws + XB_BYTES + W1B_BYTES);
    u16* W3b = (u16*)(ws + XB_BYTES + W1B_BYTES + W2B_BYTES);
    u16* h1  = (u16*)(ws + FIXED);

    int g = 16;
    while (g > 1 && FIXED + (size_t)g * PER_TREE > ws_size) g >>= 1;
    const int nG = T_TREES / g;
    u16* h2 = (u16*)(ws + FIXED + (size_t)g * (PER_TREE / 2));

    setup_kernel<<<4096 + 8192, 256, 0, stream>>>(x, xb, b3, out);
    convert_weights_kernel<<<dim3(1792, 1, T_TREES), 256, 0, stream>>>(
        W1, W2, W3, W1b, W2b, W3b);

    for (int gi = 0; gi < nG; gi++) {
        const int t0 = gi * g;
        gemm_relu_bf16<<<dim3(B_ROWS / 128, DH / 128, g), 256, 0, stream>>>(
            xb, 0, W1b + (size_t)t0 * DIN * DH, b1 + (size_t)t0 * DH, h1, B_ROWS, DH, DIN);
        gemm_relu_bf16<<<dim3(B_ROWS / 128, DH / 128, g), 256, 0, stream>>>(
            h1, (size_t)B_ROWS * DH, W2b + (size_t)t0 * DH * DH, b2 + (size_t)t0 * DH, h2, B_ROWS, DH, DH);
        gemm_final<<<dim3(B_ROWS / 128, DOUT / 128, g), 256, 0, stream>>>(
            h2, W3b + (size_t)t0 * DH * DOUT, out);
    }
}

// Round 6
// 820.601 us; speedup vs baseline: 1.0715x; 1.0715x over previous
//
#include <hip/hip_runtime.h>
#include <hip/hip_bf16.h>
#include <stdint.h>

// Problem constants
#define T_TREES 16
#define B_ROWS  8192
#define DIN     512
#define DH      1024
#define DOUT    256

typedef unsigned short u16;
typedef __attribute__((ext_vector_type(8))) short short8;
typedef __attribute__((ext_vector_type(16))) float floatx16;

// round-to-nearest-even fp32 -> bf16
__device__ __forceinline__ u16 f2bf(float f) {
    union { float f; uint32_t u; } v; v.f = f;
    uint32_t u = v.u;
    uint32_t r = (u + 0x7fffu + ((u >> 16) & 1u)) >> 16;
    return (u16)r;
}

// async 16B/lane global->LDS (lands at wave-uniform base + lane*16)
__device__ __forceinline__ void async_copy16(const u16* g, u16* l) {
    __builtin_amdgcn_global_load_lds(
        (const __attribute__((address_space(1))) uint32_t*)g,
        (__attribute__((address_space(3))) uint32_t*)l,
        16, 0, 0);
}

// ---------------------------------------------------------------------------
// Fused prep, single launch:
//   blocks [0,4096):      convert x fp32->bf16 (1,048,576 float4)
//   blocks [4096,12288):  out = mean_t b3
//   blocks [12288,40960): convert+transpose all weights (1792 tiles x 16 trees)
__global__ void prep_kernel(const float* __restrict__ x, u16* __restrict__ xb,
                            const float* __restrict__ b3, float* __restrict__ out,
                            const float* __restrict__ W1, const float* __restrict__ W2,
                            const float* __restrict__ W3,
                            u16* __restrict__ W1b, u16* __restrict__ W2b,
                            u16* __restrict__ W3b) {
    __shared__ float tile[32][33];
    if (blockIdx.x < 4096) {
        int idx = blockIdx.x * 256 + threadIdx.x;
        float4 v = ((const float4*)x)[idx];
        ushort4 o;
        o.x = f2bf(v.x); o.y = f2bf(v.y); o.z = f2bf(v.z); o.w = f2bf(v.w);
        ((ushort4*)xb)[idx] = o;
    } else if (blockIdx.x < 12288) {
        int idx = (blockIdx.x - 4096) * 256 + threadIdx.x;
        int o = idx & (DOUT - 1);
        float s = 0.f;
#pragma unroll
        for (int t = 0; t < T_TREES; t++) s += b3[t * DOUT + o];
        out[idx] = s * (1.f / T_TREES);
    } else {
        int bid = blockIdx.x - 12288;
        int t = bid / 1792, tl = bid - t * 1792;
        const float* in; u16* outp; int K, N, kt, nt; float scale = 1.f;
        if (tl < 512)       { in = W1; outp = W1b; K = DIN; N = DH;   kt = tl & 15; nt = tl >> 4; }
        else if (tl < 1536) { tl -= 512;  in = W2; outp = W2b; K = DH; N = DH;   kt = tl & 31; nt = tl >> 5; }
        else                { tl -= 1536; in = W3; outp = W3b; K = DH; N = DOUT; kt = tl & 31; nt = tl >> 5;
                              scale = 1.f / T_TREES; }
        int k0 = kt * 32, n0 = nt * 32;
        const float* inb = in + (size_t)t * K * N;
        u16* outb = outp + (size_t)t * K * N;
        int c = threadIdx.x & 31, rg = threadIdx.x >> 5;
#pragma unroll
        for (int i = 0; i < 4; i++) {
            int r = rg * 4 + i;
            tile[r][c] = inb[(size_t)(k0 + r) * N + n0 + c];
        }
        __syncthreads();
#pragma unroll
        for (int i = 0; i < 4; i++) {
            int r = rg * 4 + i;
            outb[(size_t)(n0 + r) * K + k0 + c] = f2bf(tile[c][r] * scale);
        }
    }
}

// out[idx] += sum_{t<g} Part[t][idx]   (float4 vectorized)
__global__ void reduce_kernel(const float* __restrict__ Part, float* __restrict__ Out, int g) {
    int idx = blockIdx.x * 256 + threadIdx.x;  // over 524288 float4
    float4 s = ((const float4*)Out)[idx];
    for (int t = 0; t < g; t++) {
        float4 p = ((const float4*)(Part + (size_t)t * B_ROWS * DOUT))[idx];
        s.x += p.x; s.y += p.y; s.z += p.z; s.w += p.w;
    }
    ((float4*)Out)[idx] = s;
}

// ---------------------------------------------------------------------------
// 32x32x16-MFMA GEMM core. Block 128x128, 4 waves 2x2 of 64x64, each wave
// 2x2 frags of 32x32. BK=64 slab (32 KB LDS). LDS swizzle: row r stores global
// elem-col c at LDS col c ^ ((r&3)*16); staging instr j covers rows j*8+s and
// reads global col (c8 ^ ((s&3)<<1))<<3 (full contiguous 128 B row, permuted).
// A/B frag: lane [row=lane&31][k=(lane>>5)*8..+7] b128. C/D: col=lane&31,
// row=(reg&3)+8*(reg>>2)+4*(lane>>5)  [m74/m101].

#define GEMM_PREAMBLE()                                          \
    const int tid = threadIdx.x;                                 \
    const int wave = tid >> 6;                                   \
    const int lane = tid & 63;                                   \
    const int l31 = lane & 31;                                   \
    const int h = lane >> 5;                                     \
    const int rb = l31 & 3;                                      \
    const int wm = (wave >> 1) * 64;                             \
    const int wn = (wave & 1) * 64;                              \
    const int s = lane >> 3;                                     \
    const int c8 = lane & 7;                                     \
    const int colElem = ((c8 ^ ((s & 3) << 1)) << 3);

#define GEMM_KSLAB(Ab, Bb, K)                                                         \
    {                                                                                  \
        _Pragma("unroll")                                                              \
        for (int i = 0; i < 4; i++) {                                                  \
            const int j = wave * 4 + i;                                                \
            const int r = j * 8 + s;                                                   \
            async_copy16(Ab + (size_t)(m0 + r) * K + kk + colElem, &ldsA[j * 512]);    \
            async_copy16(Bb + (size_t)(n0 + r) * K + kk + colElem, &ldsB[j * 512]);    \
        }                                                                              \
        __syncthreads();                                                               \
        _Pragma("unroll")                                                              \
        for (int kq = 0; kq < 4; kq++) {                                               \
            const int col = ((kq ^ rb) << 4) + h * 8;                                  \
            short8 a[2], b[2];                                                         \
            _Pragma("unroll")                                                          \
            for (int fi = 0; fi < 2; fi++)                                             \
                a[fi] = *(const short8*)&ldsA[(wm + fi * 32 + l31) * 64 + col];        \
            _Pragma("unroll")                                                          \
            for (int fj = 0; fj < 2; fj++)                                             \
                b[fj] = *(const short8*)&ldsB[(wn + fj * 32 + l31) * 64 + col];        \
            _Pragma("unroll")                                                          \
            for (int fi = 0; fi < 2; fi++)                                             \
                _Pragma("unroll")                                                      \
                for (int fj = 0; fj < 2; fj++)                                         \
                    acc[fi][fj] = __builtin_amdgcn_mfma_f32_32x32x16_bf16(             \
                        a[fi], b[fj], acc[fi][fj], 0, 0, 0);                           \
        }                                                                              \
        __syncthreads();                                                               \
    }

// Batched GEMM + bias + ReLU, bf16 out.  C[t] = relu(A[t] @ B[t]^T + bias[t])
__global__ __launch_bounds__(256, 2)
void gemm_relu_bf16(const u16* __restrict__ A, size_t aStrideT,
                    const u16* __restrict__ Bt,
                    const float* __restrict__ bias,
                    u16* __restrict__ C,
                    int M, int N, int K) {
    __shared__ u16 ldsA[128 * 64];
    __shared__ u16 ldsB[128 * 64];

    const int t = blockIdx.z;
    const u16* Ab = A + (size_t)t * aStrideT;
    const u16* Bb = Bt + (size_t)t * (size_t)N * K;
    u16* Cb = C + (size_t)t * (size_t)M * N;
    const float* biasb = bias + (size_t)t * N;

    const int m0 = blockIdx.x * 128;
    const int n0 = blockIdx.y * 128;

    GEMM_PREAMBLE();

    floatx16 acc[2][2];
#pragma unroll
    for (int fi = 0; fi < 2; fi++)
#pragma unroll
        for (int fj = 0; fj < 2; fj++)
#pragma unroll
            for (int r = 0; r < 16; r++) acc[fi][fj][r] = 0.f;

    for (int kk = 0; kk < K; kk += 64) GEMM_KSLAB(Ab, Bb, K);

    // epilogue: per reg, 64 lanes cover 2 rows x 32 contiguous cols = 2x64B segs
#pragma unroll
    for (int fj = 0; fj < 2; fj++) {
        const int n = n0 + wn + fj * 32 + l31;
        const float bv = biasb[n];
#pragma unroll
        for (int fi = 0; fi < 2; fi++) {
#pragma unroll
            for (int r = 0; r < 16; r++) {
                const int m = m0 + wm + fi * 32 + (r & 3) + 8 * (r >> 2) + 4 * h;
                float v = acc[fi][fj][r] + bv;
                v = v > 0.f ? v : 0.f;
                Cb[(size_t)m * N + n] = f2bf(v);
            }
        }
    }
}

// Final layer: per-tree fp32 partial planes, NO atomics.
// H2 bf16 [g][M][DH]; W3t bf16 [g][DOUT][DH] (pre-scaled by 1/16);
// Part fp32 [g][M][DOUT].
__global__ __launch_bounds__(256, 2)
void gemm_final_part(const u16* __restrict__ H2, const u16* __restrict__ W3t,
                     float* __restrict__ Part) {
    constexpr int M = B_ROWS, N = DOUT, K = DH;
    __shared__ u16 ldsA[128 * 64];
    __shared__ u16 ldsB[128 * 64];

    const int m0 = blockIdx.x * 128;
    const int n0 = blockIdx.y * 128;
    const int t = blockIdx.z;
    const u16* Ab = H2 + (size_t)t * M * K;
    const u16* Bb = W3t + (size_t)t * N * K;
    float* Pb = Part + (size_t)t * M * N;

    GEMM_PREAMBLE();

    floatx16 acc[2][2];
#pragma unroll
    for (int fi = 0; fi < 2; fi++)
#pragma unroll
        for (int fj = 0; fj < 2; fj++)
#pragma unroll
            for (int r = 0; r < 16; r++) acc[fi][fj][r] = 0.f;

    for (int kk = 0; kk < K; kk += 64) GEMM_KSLAB(Ab, Bb, K);

#pragma unroll
    for (int fj = 0; fj < 2; fj++) {
        const int n = n0 + wn + fj * 32 + l31;
#pragma unroll
        for (int fi = 0; fi < 2; fi++) {
#pragma unroll
            for (int r = 0; r < 16; r++) {
                const int m = m0 + wm + fi * 32 + (r & 3) + 8 * (r >> 2) + 4 * h;
                Pb[(size_t)m * N + n] = acc[fi][fj][r];
            }
        }
    }
}

// ---------------------------------------------------------------------------
extern "C" void kernel_launch(void* const* d_in, const int* in_sizes, int n_in,
                              void* d_out, int out_size, void* d_ws, size_t ws_size,
                              hipStream_t stream) {
    const float* x  = (const float*)d_in[0];
    const float* W1 = (const float*)d_in[1];
    const float* b1 = (const float*)d_in[2];
    const float* W2 = (const float*)d_in[3];
    const float* b2 = (const float*)d_in[4];
    const float* W3 = (const float*)d_in[5];
    const float* b3 = (const float*)d_in[6];
    float* out = (float*)d_out;

    // workspace: fixed 64 MB (xb 8 + W1b 16 + W2b 32 + W3b 8), then h1/h2.
    // Partial planes (g x 8 MB fp32) reuse the h1 region (free after L2).
    const size_t XB_BYTES = 8388608ull;
    const size_t W1B_BYTES = 16777216ull, W2B_BYTES = 33554432ull, W3B_BYTES = 8388608ull;
    const size_t FIXED = XB_BYTES + W1B_BYTES + W2B_BYTES + W3B_BYTES;  // 67,108,864
    const size_t PER_TREE = 33554432ull;  // h1 16 MB + h2 16 MB

    uint8_t* ws = (uint8_t*)d_ws;
    u16* xb  = (u16*)ws;
    u16* W1b = (u16*)(ws + XB_BYTES);
    u16* W2b = (u16*)(ws + XB_BYTES + W1B_BYTES);
    u16* W3b = (u16*)(ws + XB_BYTES + W1B_BYTES + W2B_BYTES);
    u16* h1  = (u16*)(ws + FIXED);
    float* part = (float*)(ws + FIXED);   // aliases h1 (safe: h1 dead after L2)

    int g = 16;
    while (g > 1 && FIXED + (size_t)g * PER_TREE > ws_size) g >>= 1;
    const int nG = T_TREES / g;
    u16* h2 = (u16*)(ws + FIXED + (size_t)g * (PER_TREE / 2));

    prep_kernel<<<12288 + 1792 * T_TREES, 256, 0, stream>>>(
        x, xb, b3, out, W1, W2, W3, W1b, W2b, W3b);

    for (int gi = 0; gi < nG; gi++) {
        const int t0 = gi * g;
        gemm_relu_bf16<<<dim3(B_ROWS / 128, DH / 128, g), 256, 0, stream>>>(
            xb, 0, W1b + (size_t)t0 * DIN * DH, b1 + (size_t)t0 * DH, h1, B_ROWS, DH, DIN);
        gemm_relu_bf16<<<dim3(B_ROWS / 128, DH / 128, g), 256, 0, stream>>>(
            h1, (size_t)B_ROWS * DH, W2b + (size_t)t0 * DH * DH, b2 + (size_t)t0 * DH, h2, B_ROWS, DH, DH);
        gemm_final_part<<<dim3(B_ROWS / 128, DOUT / 128, g), 256, 0, stream>>>(
            h2, W3b + (size_t)t0 * DH * DOUT, part);
        reduce_kernel<<<(B_ROWS * DOUT / 4) / 256, 256, 0, stream>>>(part, out, g);
    }
}